// Round 4
// baseline (233.165 us; speedup 1.0000x reference)
//
#include <hip/hip_runtime.h>
#include <hip/hip_bf16.h>
#include <math.h>

#define NNODES 20000
#define NEDGES 320000

using f32x4 = __attribute__((ext_vector_type(4))) float;
using s16x8 = __attribute__((ext_vector_type(8))) short;
using u16x8 = __attribute__((ext_vector_type(8))) unsigned short;

__device__ __forceinline__ float bf2f(unsigned short u) {
    union { unsigned int i; float f; } c; c.i = ((unsigned int)u) << 16; return c.f;
}
__device__ __forceinline__ unsigned short f2bf(float f) {
    __hip_bfloat16 h = __float2bfloat16(f);
    return *reinterpret_cast<unsigned short*>(&h);
}
__device__ __forceinline__ u16x8 packA(const float4& x, const float4& y) {
    u16x8 u; u[0]=f2bf(x.x); u[1]=f2bf(x.y); u[2]=f2bf(x.z); u[3]=f2bf(x.w);
             u[4]=f2bf(y.x); u[5]=f2bf(y.y); u[6]=f2bf(y.z); u[7]=f2bf(y.w);
    return u;
}

// ---------------------------------------------------------------------------
// prep + hist fused (disjoint gid ranges; counts pre-zeroed by memsetAsync).
// Head-major column c = head*32+dim <-> original col n_old = dim*8+head.
// ---------------------------------------------------------------------------
__global__ __launch_bounds__(256) void prep_hist_k(
    const float* __restrict__ Wq, const float* __restrict__ bq,
    const float* __restrict__ Wk, const float* __restrict__ bk,
    const float* __restrict__ Wv, const float* __restrict__ bv,
    const float* __restrict__ Wo, const int* __restrict__ rows,
    unsigned short* __restrict__ wt, float* __restrict__ bp,
    int* __restrict__ counts)
{
    const int gid = blockIdx.x * 256 + threadIdx.x;
    const float SC = 0.17677669529663687f;  // 32^-0.5
    if (gid < 262144) {
        const int mat = gid >> 16, r = gid & 65535;
        if (mat < 3) {
            const int k = r >> 8, c = r & 255;
            const int n_old = ((c & 31) << 3) | (c >> 5);
            const float* W = (mat == 0) ? Wq : (mat == 1) ? Wk : Wv;
            float val = W[k * 256 + n_old];
            if (mat == 0) val *= SC;
            wt[mat * 65536 + c * 256 + k] = f2bf(val);
        } else {
            const int c = r >> 8, n = r & 255;
            const int n_old = ((c & 31) << 3) | (c >> 5);
            wt[3 * 65536 + n * 256 + c] = f2bf(Wo[n_old * 256 + n]);
        }
    } else if (gid < 262912) {
        const int idx = gid - 262144;
        const int mat = idx >> 8, c = idx & 255;
        const int n_old = ((c & 31) << 3) | (c >> 5);
        const float* b = (mat == 0) ? bq : (mat == 1) ? bk : bv;
        float val = b[n_old];
        if (mat == 0) val *= SC;
        bp[mat * 256 + c] = val;
    } else if (gid < 262912 + NEDGES) {
        atomicAdd(&counts[rows[gid - 262912]], 1);
    }
}

// ---------------------------------------------------------------------------
// single-pass exclusive scan: 1024 threads x 20 contiguous elements
// ---------------------------------------------------------------------------
__global__ __launch_bounds__(1024) void scan_k(const int* __restrict__ counts,
                                               int* __restrict__ row_start)
{
    __shared__ int wsum[16];
    const int t = threadIdx.x, lane = t & 63, w = t >> 6;
    const int base = t * 20;
    int c[20]; int s = 0;
    #pragma unroll
    for (int j = 0; j < 20; ++j) {
        const int idx = base + j;
        c[j] = (idx < NNODES) ? counts[idx] : 0;
        s += c[j];
    }
    int incl = s;
    #pragma unroll
    for (int off = 1; off < 64; off <<= 1) {
        const int y = __shfl_up(incl, off);
        if (lane >= off) incl += y;
    }
    if (lane == 63) wsum[w] = incl;
    __syncthreads();
    int prev = 0;
    for (int i = 0; i < w; ++i) prev += wsum[i];
    int run = prev + incl - s;
    if (t == 0) row_start[0] = 0;
    #pragma unroll
    for (int j = 0; j < 20; ++j) {
        const int idx = base + j;
        run += c[j];
        if (idx < NNODES) row_start[idx + 1] = run;
    }
}

__global__ void scatter_k(const int* __restrict__ rows, const int* __restrict__ cols,
                          const int* __restrict__ row_start, int* __restrict__ cursor,
                          int* __restrict__ cols_sorted)
{
    const int i = blockIdx.x * blockDim.x + threadIdx.x;
    if (i < NEDGES) {
        const int r = rows[i];
        const int pos = row_start[r] + atomicAdd(&cursor[r], 1);
        cols_sorted[pos] = cols[i];
    }
}

// ---------------------------------------------------------------------------
// QKV GEMM, bf16 MFMA 16x16x32, 128x128 tile, BK=32, 4 waves, double-buffered
// LDS; next-tile global loads issued before current tile's MFMAs; fp32->bf16
// conversion deferred to ds_write (vmcnt wait lands after MFMAs).
// kv epilogue writes interleaved {k0..3, v0..3} per 4-dim group.
// ---------------------------------------------------------------------------
__global__ __launch_bounds__(256) void qkv_mfma_k(
    const float* __restrict__ h,
    const unsigned short* __restrict__ wt, const float* __restrict__ bp,
    unsigned short* __restrict__ qo, unsigned short* __restrict__ kv)
{
    const int bm = blockIdx.x * 128;
    const int mat = blockIdx.y >> 1;
    const int bn = (blockIdx.y & 1) * 128;
    const unsigned short* W = wt + mat * 65536;
    const float* bias = bp + mat * 256;

    __shared__ __align__(16) unsigned short As[2][128][40];
    __shared__ __align__(16) unsigned short Bs[2][128][40];

    const int t = threadIdx.x;
    const int lane = t & 63, w = t >> 6;
    const int wr = (w >> 1) * 64, wc = (w & 1) * 64;

    f32x4 acc[4][4];
    #pragma unroll
    for (int i = 0; i < 4; ++i)
        #pragma unroll
        for (int j = 0; j < 4; ++j) acc[i][j] = (f32x4){0.f, 0.f, 0.f, 0.f};

    const int srow = t >> 2, koff = (t & 3) * 8;
    const int m0 = min(bm + srow, NNODES - 1);
    const int m1 = min(bm + srow + 64, NNODES - 1);
    const float* pa0 = h + m0 * 256 + koff;
    const float* pa1 = h + m1 * 256 + koff;
    const unsigned short* pb0 = W + (bn + srow) * 256 + koff;
    const unsigned short* pb1 = W + (bn + srow + 64) * 256 + koff;

    float4 fa0a = *(const float4*)(pa0), fa0b = *(const float4*)(pa0 + 4);
    float4 fa1a = *(const float4*)(pa1), fa1b = *(const float4*)(pa1 + 4);
    u16x8 rb0 = *(const u16x8*)(pb0), rb1 = *(const u16x8*)(pb1);

    *(u16x8*)&As[0][srow][koff]      = packA(fa0a, fa0b);
    *(u16x8*)&As[0][srow + 64][koff] = packA(fa1a, fa1b);
    *(u16x8*)&Bs[0][srow][koff]      = rb0;
    *(u16x8*)&Bs[0][srow + 64][koff] = rb1;
    __syncthreads();

    #pragma unroll
    for (int kt = 0; kt < 8; ++kt) {
        const int cur = kt & 1;
        if (kt < 7) {   // issue next-tile loads before MFMAs
            const int k0 = (kt + 1) * 32;
            fa0a = *(const float4*)(pa0 + k0); fa0b = *(const float4*)(pa0 + k0 + 4);
            fa1a = *(const float4*)(pa1 + k0); fa1b = *(const float4*)(pa1 + k0 + 4);
            rb0 = *(const u16x8*)(pb0 + k0);   rb1 = *(const u16x8*)(pb1 + k0);
        }
        s16x8 a[4], b[4];
        const int kk = (lane >> 4) * 8;
        #pragma unroll
        for (int i = 0; i < 4; ++i) {
            a[i] = *(const s16x8*)&As[cur][wr + i * 16 + (lane & 15)][kk];
            b[i] = *(const s16x8*)&Bs[cur][wc + i * 16 + (lane & 15)][kk];
        }
        #pragma unroll
        for (int i = 0; i < 4; ++i)
            #pragma unroll
            for (int j = 0; j < 4; ++j)
                acc[i][j] = __builtin_amdgcn_mfma_f32_16x16x32_bf16(a[i], b[j], acc[i][j], 0, 0, 0);
        if (kt < 7) {
            __syncthreads();
            *(u16x8*)&As[cur ^ 1][srow][koff]      = packA(fa0a, fa0b);
            *(u16x8*)&As[cur ^ 1][srow + 64][koff] = packA(fa1a, fa1b);
            *(u16x8*)&Bs[cur ^ 1][srow][koff]      = rb0;
            *(u16x8*)&Bs[cur ^ 1][srow + 64][koff] = rb1;
            __syncthreads();
        }
    }
    #pragma unroll
    for (int i = 0; i < 4; ++i)
        #pragma unroll
        for (int j = 0; j < 4; ++j) {
            const int n = bn + wc + j * 16 + (lane & 15);
            const float bval = bias[n];
            const int kvbase = ((n >> 2) << 3) + (n & 3) + ((mat == 2) ? 4 : 0);
            #pragma unroll
            for (int r = 0; r < 4; ++r) {
                const int m = bm + wr + i * 16 + (lane >> 4) * 4 + r;
                if (m < NNODES) {
                    const unsigned short val = f2bf(acc[i][j][r] + bval);
                    if (mat == 0) qo[m * 256 + n] = val;
                    else          kv[m * 512 + kvbase] = val;
                }
            }
        }
}

// Output projection (bf16 A), same double-buffered structure
__global__ __launch_bounds__(256) void out_mfma_k(
    const unsigned short* __restrict__ A,
    const unsigned short* __restrict__ wt, const float* __restrict__ bo,
    float* __restrict__ C)
{
    const int bm = blockIdx.x * 128;
    const int bn = blockIdx.y * 128;
    const unsigned short* W = wt + 3 * 65536;

    __shared__ __align__(16) unsigned short As[2][128][40];
    __shared__ __align__(16) unsigned short Bs[2][128][40];

    const int t = threadIdx.x;
    const int lane = t & 63, w = t >> 6;
    const int wr = (w >> 1) * 64, wc = (w & 1) * 64;

    f32x4 acc[4][4];
    #pragma unroll
    for (int i = 0; i < 4; ++i)
        #pragma unroll
        for (int j = 0; j < 4; ++j) acc[i][j] = (f32x4){0.f, 0.f, 0.f, 0.f};

    const int srow = t >> 2, koff = (t & 3) * 8;
    const int m0 = min(bm + srow, NNODES - 1);
    const int m1 = min(bm + srow + 64, NNODES - 1);
    const unsigned short* pa0 = A + m0 * 256 + koff;
    const unsigned short* pa1 = A + m1 * 256 + koff;
    const unsigned short* pb0 = W + (bn + srow) * 256 + koff;
    const unsigned short* pb1 = W + (bn + srow + 64) * 256 + koff;

    u16x8 ra0 = *(const u16x8*)(pa0), ra1 = *(const u16x8*)(pa1);
    u16x8 rb0 = *(const u16x8*)(pb0), rb1 = *(const u16x8*)(pb1);

    *(u16x8*)&As[0][srow][koff]      = ra0;
    *(u16x8*)&As[0][srow + 64][koff] = ra1;
    *(u16x8*)&Bs[0][srow][koff]      = rb0;
    *(u16x8*)&Bs[0][srow + 64][koff] = rb1;
    __syncthreads();

    #pragma unroll
    for (int kt = 0; kt < 8; ++kt) {
        const int cur = kt & 1;
        if (kt < 7) {
            const int k0 = (kt + 1) * 32;
            ra0 = *(const u16x8*)(pa0 + k0); ra1 = *(const u16x8*)(pa1 + k0);
            rb0 = *(const u16x8*)(pb0 + k0); rb1 = *(const u16x8*)(pb1 + k0);
        }
        s16x8 a[4], b[4];
        const int kk = (lane >> 4) * 8;
        #pragma unroll
        for (int i = 0; i < 4; ++i) {
            a[i] = *(const s16x8*)&As[cur][wr + i * 16 + (lane & 15)][kk];
            b[i] = *(const s16x8*)&Bs[cur][wc + i * 16 + (lane & 15)][kk];
        }
        #pragma unroll
        for (int i = 0; i < 4; ++i)
            #pragma unroll
            for (int j = 0; j < 4; ++j)
                acc[i][j] = __builtin_amdgcn_mfma_f32_16x16x32_bf16(a[i], b[j], acc[i][j], 0, 0, 0);
        if (kt < 7) {
            __syncthreads();
            *(u16x8*)&As[cur ^ 1][srow][koff]      = ra0;
            *(u16x8*)&As[cur ^ 1][srow + 64][koff] = ra1;
            *(u16x8*)&Bs[cur ^ 1][srow][koff]      = rb0;
            *(u16x8*)&Bs[cur ^ 1][srow + 64][koff] = rb1;
            __syncthreads();
        }
    }
    #pragma unroll
    for (int i = 0; i < 4; ++i)
        #pragma unroll
        for (int j = 0; j < 4; ++j) {
            const int n = bn + wc + j * 16 + (lane & 15);
            const float bval = bo[n];
            #pragma unroll
            for (int r = 0; r < 4; ++r) {
                const int m = bm + wr + i * 16 + (lane >> 4) * 4 + r;
                if (m < NNODES) C[m * 256 + n] = acc[i][j][r] + bval;
            }
        }
}

// ---------------------------------------------------------------------------
// Fused SDDMM + softmax + SPMM. One wave per row, row hoisted to SGPR so the
// column list is read via SCALAR loads (no per-edge DS broadcast chain).
// Batch-8: 8 independent kv loads in flight before any compute. Tail edges
// clamp to deg-1 (dup load = L1 hit) and zero their exp contribution.
// ---------------------------------------------------------------------------
__global__ __launch_bounds__(256) void row_attn_k(
    const unsigned short* __restrict__ q, const unsigned short* __restrict__ kv,
    const int* __restrict__ row_start, const int* __restrict__ cols_sorted,
    unsigned short* __restrict__ ot)
{
    const int lane = threadIdx.x & 63;
    const int row = __builtin_amdgcn_readfirstlane(blockIdx.x * 4 + (threadIdx.x >> 6));
    const int rs = row_start[row];          // s_load
    const int re = row_start[row + 1];      // s_load
    const int deg = re - rs;

    const ushort4 qu = *reinterpret_cast<const ushort4*>(&q[row * 256 + lane * 4]);
    const float q0 = bf2f(qu.x), q1 = bf2f(qu.y), q2 = bf2f(qu.z), q3 = bf2f(qu.w);
    float z = 0.f, o0 = 0.f, o1 = 0.f, o2 = 0.f, o3 = 0.f;

    const int* cp = cols_sorted + rs;       // SGPR base
    for (int i0 = 0; i0 < deg; i0 += 8) {
        u16x8 kvb[8];
        #pragma unroll
        for (int j = 0; j < 8; ++j) {
            const int jj = min(i0 + j, deg - 1);   // SALU
            const int cn = cp[jj];                 // s_load (uniform)
            kvb[j] = *reinterpret_cast<const u16x8*>(&kv[cn * 512 + lane * 8]);
        }
        #pragma unroll
        for (int j = 0; j < 8; ++j) {
            float p = q0 * bf2f(kvb[j][0]);
            p = fmaf(q1, bf2f(kvb[j][1]), p);
            p = fmaf(q2, bf2f(kvb[j][2]), p);
            p = fmaf(q3, bf2f(kvb[j][3]), p);
            p += __shfl_xor(p, 1);
            p += __shfl_xor(p, 2);
            p += __shfl_xor(p, 4);
            const float e = (i0 + j < deg) ? __expf(p) : 0.f;   // uniform select
            z += e;
            o0 = fmaf(e, bf2f(kvb[j][4]), o0);
            o1 = fmaf(e, bf2f(kvb[j][5]), o1);
            o2 = fmaf(e, bf2f(kvb[j][6]), o2);
            o3 = fmaf(e, bf2f(kvb[j][7]), o3);
        }
    }
    ushort4 r;
    if (deg > 0) {
        const float iz = 1.0f / z;
        r.x = f2bf(o0 * iz); r.y = f2bf(o1 * iz);
        r.z = f2bf(o2 * iz); r.w = f2bf(o3 * iz);
    } else {
        r.x = r.y = r.z = r.w = 0;
    }
    *reinterpret_cast<ushort4*>(&ot[row * 256 + lane * 4]) = r;
}

// ---------------------------------------------------------------------------
extern "C" void kernel_launch(void* const* d_in, const int* in_sizes, int n_in,
                              void* d_out, int out_size, void* d_ws, size_t ws_size,
                              hipStream_t stream)
{
    const float* h  = (const float*)d_in[0];
    const float* Wq = (const float*)d_in[1];
    const float* bq = (const float*)d_in[2];
    const float* Wk = (const float*)d_in[3];
    const float* bk = (const float*)d_in[4];
    const float* Wv = (const float*)d_in[5];
    const float* bv = (const float*)d_in[6];
    const float* Wo = (const float*)d_in[7];
    const float* bo = (const float*)d_in[8];
    const int* rows = (const int*)d_in[9];
    const int* cols = (const int*)d_in[10];
    float* outp = (float*)d_out;

    // workspace layout (bytes), 16B-aligned; total ~43 MB (+ tail pad for
    // the batch-8 scalar col reads that may run 28B past cols_sorted)
    char* ws = (char*)d_ws;
    unsigned short* q_b  = (unsigned short*)(ws + 0);          // 10,240,000
    unsigned short* kv_b = (unsigned short*)(ws + 10240000);   // 20,480,000
    unsigned short* ot_b = (unsigned short*)(ws + 30720000);   // 10,240,000
    unsigned short* wt   = (unsigned short*)(ws + 40960000);   // 524,288
    float* bp            = (float*)(ws + 41484288);            // 3,072
    int* row_start       = (int*)(ws + 41487360);              // 80,004
    int* counts          = (int*)(ws + 41567488);              // 80,000
    int* cursor          = (int*)(ws + 41647488);              // 80,000
    int* cols_sorted     = (int*)(ws + 41727488);              // 1,280,000 + 64 pad

    hipMemsetAsync(ws + 41567488, 0, 160000, stream);          // counts + cursor

    prep_hist_k<<<2277, 256, 0, stream>>>(Wq, bq, Wk, bk, Wv, bv, Wo, rows,
                                          wt, bp, counts);
    scan_k<<<1, 1024, 0, stream>>>(counts, row_start);
    scatter_k<<<1250, 256, 0, stream>>>(rows, cols, row_start, cursor, cols_sorted);
    qkv_mfma_k<<<dim3(157, 6), 256, 0, stream>>>(h, wt, bp, q_b, kv_b);
    row_attn_k<<<5000, 256, 0, stream>>>(q_b, kv_b, row_start, cols_sorted, ot_b);
    out_mfma_k<<<dim3(157, 2), 256, 0, stream>>>(ot_b, wt, bo, outp);
}

// Round 5
// 222.859 us; speedup vs baseline: 1.0462x; 1.0462x over previous
//
#include <hip/hip_runtime.h>
#include <hip/hip_bf16.h>
#include <math.h>

#define NNODES 20000
#define NEDGES 320000

using f32x4 = __attribute__((ext_vector_type(4))) float;
using s16x8 = __attribute__((ext_vector_type(8))) short;
using u16x8 = __attribute__((ext_vector_type(8))) unsigned short;

__device__ __forceinline__ float bf2f(unsigned short u) {
    union { unsigned int i; float f; } c; c.i = ((unsigned int)u) << 16; return c.f;
}
__device__ __forceinline__ unsigned short f2bf(float f) {
    __hip_bfloat16 h = __float2bfloat16(f);
    return *reinterpret_cast<unsigned short*>(&h);
}
// cross-lane add via DPP quad_perm (VALU pipe -- no lgkmcnt interference)
template <int CTRL>
__device__ __forceinline__ float dpp_xadd(float x) {
    union { float f; int i; } a, b;
    a.f = x;
    b.i = __builtin_amdgcn_update_dpp(0, a.i, CTRL, 0xf, 0xf, true);
    return x + b.f;
}

// ---------------------------------------------------------------------------
// prep + hist + hcvt fused (disjoint gid ranges; counts pre-zeroed).
// Head-major col c = head*32+dim <-> original col n_old = dim*8+head.
// q weights/bias additionally scaled by 32^-0.5 * log2(e)  (exp -> exp2).
// ---------------------------------------------------------------------------
__global__ __launch_bounds__(256) void prep_all_k(
    const float* __restrict__ Wq, const float* __restrict__ bq,
    const float* __restrict__ Wk, const float* __restrict__ bk,
    const float* __restrict__ Wv, const float* __restrict__ bv,
    const float* __restrict__ Wo, const int* __restrict__ rows,
    const float* __restrict__ h,
    unsigned short* __restrict__ wt, float* __restrict__ bp,
    int* __restrict__ counts, unsigned short* __restrict__ hb)
{
    const int gid = blockIdx.x * 256 + threadIdx.x;
    const float SCQ = 0.17677669529663687f * 1.4426950408889634f;
    if (gid < 262144) {
        const int mat = gid >> 16, r = gid & 65535;
        if (mat < 3) {
            const int k = r >> 8, c = r & 255;
            const int n_old = ((c & 31) << 3) | (c >> 5);
            const float* W = (mat == 0) ? Wq : (mat == 1) ? Wk : Wv;
            float val = W[k * 256 + n_old];
            if (mat == 0) val *= SCQ;
            wt[mat * 65536 + c * 256 + k] = f2bf(val);
        } else {
            const int c = r >> 8, n = r & 255;
            const int n_old = ((c & 31) << 3) | (c >> 5);
            wt[3 * 65536 + n * 256 + c] = f2bf(Wo[n_old * 256 + n]);
        }
    } else if (gid < 262912) {
        const int idx = gid - 262144;
        const int mat = idx >> 8, c = idx & 255;
        const int n_old = ((c & 31) << 3) | (c >> 5);
        const float* b = (mat == 0) ? bq : (mat == 1) ? bk : bv;
        float val = b[n_old];
        if (mat == 0) val *= SCQ;
        bp[mat * 256 + c] = val;
    } else if (gid < 582912) {
        atomicAdd(&counts[rows[gid - 262912]], 1);
    } else {  // gid < 1,862,912 : h -> bf16, 4 elements each
        const int i = (gid - 582912) * 4;
        const float4 f = *reinterpret_cast<const float4*>(&h[i]);
        ushort4 u;
        u.x = f2bf(f.x); u.y = f2bf(f.y); u.z = f2bf(f.z); u.w = f2bf(f.w);
        *reinterpret_cast<ushort4*>(&hb[i]) = u;
    }
}

// ---------------------------------------------------------------------------
// single-pass exclusive scan: 1024 threads x 20 contiguous elements
// ---------------------------------------------------------------------------
__global__ __launch_bounds__(1024) void scan_k(const int* __restrict__ counts,
                                               int* __restrict__ row_start)
{
    __shared__ int wsum[16];
    const int t = threadIdx.x, lane = t & 63, w = t >> 6;
    const int base = t * 20;
    int c[20]; int s = 0;
    #pragma unroll
    for (int j = 0; j < 20; ++j) {
        const int idx = base + j;
        c[j] = (idx < NNODES) ? counts[idx] : 0;
        s += c[j];
    }
    int incl = s;
    #pragma unroll
    for (int off = 1; off < 64; off <<= 1) {
        const int y = __shfl_up(incl, off);
        if (lane >= off) incl += y;
    }
    if (lane == 63) wsum[w] = incl;
    __syncthreads();
    int prev = 0;
    for (int i = 0; i < w; ++i) prev += wsum[i];
    int run = prev + incl - s;
    if (t == 0) row_start[0] = 0;
    #pragma unroll
    for (int j = 0; j < 20; ++j) {
        const int idx = base + j;
        run += c[j];
        if (idx < NNODES) row_start[idx + 1] = run;
    }
}

__global__ void scatter_k(const int* __restrict__ rows, const int* __restrict__ cols,
                          const int* __restrict__ row_start, int* __restrict__ cursor,
                          int* __restrict__ cols_sorted)
{
    const int i = blockIdx.x * blockDim.x + threadIdx.x;
    if (i < NEDGES) {
        const int r = rows[i];
        const int pos = row_start[r] + atomicAdd(&cursor[r], 1);
        cols_sorted[pos] = cols[i];
    }
}

// ---------------------------------------------------------------------------
// QKV GEMM: 64x128 tile (1878 blocks -> high TLP), BK=32, 4 waves (2Mx2N),
// bf16 A from hb. kv epilogue layout (per node, 512 shorts):
//   group g = head*4 + dimgrp (dimgrp = dim>>3): [g*16 .. g*16+7] = k dims,
//   [g*16+8 .. g*16+15] = v dims  -> kvbase = ((n>>3)<<4) + (n&7) + (mat==2?8:0)
// ---------------------------------------------------------------------------
__global__ __launch_bounds__(256) void qkv_mfma_k(
    const unsigned short* __restrict__ hb,
    const unsigned short* __restrict__ wt, const float* __restrict__ bp,
    unsigned short* __restrict__ qo, unsigned short* __restrict__ kv)
{
    const int bm = blockIdx.x * 64;
    const int mat = blockIdx.y >> 1;
    const int bn = (blockIdx.y & 1) * 128;
    const unsigned short* W = wt + mat * 65536;
    const float* bias = bp + mat * 256;

    __shared__ __align__(16) unsigned short As[64][40];
    __shared__ __align__(16) unsigned short Bs[128][40];

    const int t = threadIdx.x;
    const int lane = t & 63, w = t >> 6;
    const int wr = (w >> 1) * 32, wc = (w & 1) * 64;

    f32x4 acc[2][4];
    #pragma unroll
    for (int i = 0; i < 2; ++i)
        #pragma unroll
        for (int j = 0; j < 4; ++j) acc[i][j] = (f32x4){0.f, 0.f, 0.f, 0.f};

    const int arow = t >> 2, koff = (t & 3) * 8;
    const int m0 = min(bm + arow, NNODES - 1);
    const unsigned short* pa  = hb + m0 * 256 + koff;
    const unsigned short* pb0 = W + (bn + arow) * 256 + koff;
    const unsigned short* pb1 = W + (bn + arow + 64) * 256 + koff;

    u16x8 ra  = *(const u16x8*)(pa);
    u16x8 rb0 = *(const u16x8*)(pb0);
    u16x8 rb1 = *(const u16x8*)(pb1);

    #pragma unroll
    for (int kt = 0; kt < 8; ++kt) {
        __syncthreads();              // prev iteration's frag reads done
        *(u16x8*)&As[arow][koff]      = ra;
        *(u16x8*)&Bs[arow][koff]      = rb0;
        *(u16x8*)&Bs[arow + 64][koff] = rb1;
        __syncthreads();
        if (kt < 7) {                 // issue next-tile loads before MFMAs
            const int k0 = (kt + 1) * 32;
            ra  = *(const u16x8*)(pa + k0);
            rb0 = *(const u16x8*)(pb0 + k0);
            rb1 = *(const u16x8*)(pb1 + k0);
        }
        s16x8 a[2], b[4];
        const int kk = (lane >> 4) * 8;
        #pragma unroll
        for (int i = 0; i < 2; ++i)
            a[i] = *(const s16x8*)&As[wr + i * 16 + (lane & 15)][kk];
        #pragma unroll
        for (int j = 0; j < 4; ++j)
            b[j] = *(const s16x8*)&Bs[wc + j * 16 + (lane & 15)][kk];
        #pragma unroll
        for (int i = 0; i < 2; ++i)
            #pragma unroll
            for (int j = 0; j < 4; ++j)
                acc[i][j] = __builtin_amdgcn_mfma_f32_16x16x32_bf16(a[i], b[j], acc[i][j], 0, 0, 0);
    }
    #pragma unroll
    for (int i = 0; i < 2; ++i)
        #pragma unroll
        for (int j = 0; j < 4; ++j) {
            const int n = bn + wc + j * 16 + (lane & 15);
            const float bval = bias[n];
            const int kvbase = ((n >> 3) << 4) + (n & 7) + ((mat == 2) ? 8 : 0);
            #pragma unroll
            for (int r = 0; r < 4; ++r) {
                const int m = bm + wr + i * 16 + (lane >> 4) * 4 + r;
                if (m < NNODES) {
                    const unsigned short val = f2bf(acc[i][j][r] + bval);
                    if (mat == 0) qo[m * 256 + n] = val;
                    else          kv[m * 512 + kvbase] = val;
                }
            }
        }
}

// Output projection: 64x128 tile, fp32 out = ot(bf16) @ Wot + bo
__global__ __launch_bounds__(256) void out_mfma_k(
    const unsigned short* __restrict__ A,
    const unsigned short* __restrict__ wt, const float* __restrict__ bo,
    float* __restrict__ C)
{
    const int bm = blockIdx.x * 64;
    const int bn = blockIdx.y * 128;
    const unsigned short* W = wt + 3 * 65536;

    __shared__ __align__(16) unsigned short As[64][40];
    __shared__ __align__(16) unsigned short Bs[128][40];

    const int t = threadIdx.x;
    const int lane = t & 63, w = t >> 6;
    const int wr = (w >> 1) * 32, wc = (w & 1) * 64;

    f32x4 acc[2][4];
    #pragma unroll
    for (int i = 0; i < 2; ++i)
        #pragma unroll
        for (int j = 0; j < 4; ++j) acc[i][j] = (f32x4){0.f, 0.f, 0.f, 0.f};

    const int arow = t >> 2, koff = (t & 3) * 8;
    const int m0 = min(bm + arow, NNODES - 1);
    const unsigned short* pa  = A + m0 * 256 + koff;
    const unsigned short* pb0 = W + (bn + arow) * 256 + koff;
    const unsigned short* pb1 = W + (bn + arow + 64) * 256 + koff;

    u16x8 ra  = *(const u16x8*)(pa);
    u16x8 rb0 = *(const u16x8*)(pb0);
    u16x8 rb1 = *(const u16x8*)(pb1);

    #pragma unroll
    for (int kt = 0; kt < 8; ++kt) {
        __syncthreads();
        *(u16x8*)&As[arow][koff]      = ra;
        *(u16x8*)&Bs[arow][koff]      = rb0;
        *(u16x8*)&Bs[arow + 64][koff] = rb1;
        __syncthreads();
        if (kt < 7) {
            const int k0 = (kt + 1) * 32;
            ra  = *(const u16x8*)(pa + k0);
            rb0 = *(const u16x8*)(pb0 + k0);
            rb1 = *(const u16x8*)(pb1 + k0);
        }
        s16x8 a[2], b[4];
        const int kk = (lane >> 4) * 8;
        #pragma unroll
        for (int i = 0; i < 2; ++i)
            a[i] = *(const s16x8*)&As[wr + i * 16 + (lane & 15)][kk];
        #pragma unroll
        for (int j = 0; j < 4; ++j)
            b[j] = *(const s16x8*)&Bs[wc + j * 16 + (lane & 15)][kk];
        #pragma unroll
        for (int i = 0; i < 2; ++i)
            #pragma unroll
            for (int j = 0; j < 4; ++j)
                acc[i][j] = __builtin_amdgcn_mfma_f32_16x16x32_bf16(a[i], b[j], acc[i][j], 0, 0, 0);
    }
    #pragma unroll
    for (int i = 0; i < 2; ++i)
        #pragma unroll
        for (int j = 0; j < 4; ++j) {
            const int n = bn + wc + j * 16 + (lane & 15);
            const float bval = bo[n];
            #pragma unroll
            for (int r = 0; r < 4; ++r) {
                const int m = bm + wr + i * 16 + (lane >> 4) * 4 + r;
                if (m < NNODES) C[m * 256 + n] = acc[i][j][r] + bval;
            }
        }
}

// ---------------------------------------------------------------------------
// Fused SDDMM + softmax + SPMM. One wave per row; HALF-WAVE per edge
// (2 edges/iter). Lane (within half) w5: head w5>>2, dims (w5&3)*8..+7.
// Head-dot reduce = 2 DPP quad_perm adds (pure VALU -- no lgkm in loop).
// Col indices via scalar loads; batch-4-edge ping-pong for MLP.
// ---------------------------------------------------------------------------
__global__ __launch_bounds__(256) void row_attn_k(
    const unsigned short* __restrict__ q, const unsigned short* __restrict__ kv,
    const int* __restrict__ row_start, const int* __restrict__ cols_sorted,
    unsigned short* __restrict__ ot)
{
    const int lane = threadIdx.x & 63;
    const int w5 = lane & 31;
    const int half = lane >> 5;
    const int row = __builtin_amdgcn_readfirstlane(blockIdx.x * 4 + (threadIdx.x >> 6));
    const int rs = row_start[row];
    const int re = row_start[row + 1];
    const int deg = re - rs;

    float qd[8];
    {
        const u16x8 qu = *reinterpret_cast<const u16x8*>(&q[row * 256 + w5 * 8]);
        #pragma unroll
        for (int d = 0; d < 8; ++d) qd[d] = bf2f(qu[d]);
    }
    float o[8] = {0.f, 0.f, 0.f, 0.f, 0.f, 0.f, 0.f, 0.f};
    float z = 0.f;
    const int* cp = cols_sorted + rs;

#define LP(K, V, base) do { \
    const int c0 = cp[min((base), deg - 1)]; \
    const int c1 = cp[min((base) + 1, deg - 1)]; \
    const int cn = half ? c1 : c0; \
    const unsigned short* p_ = kv + cn * 512 + w5 * 16; \
    K = *reinterpret_cast<const u16x8*>(p_); \
    V = *reinterpret_cast<const u16x8*>(p_ + 8); \
} while (0)

#define CMP(K, V, base) do { \
    float pa_ = qd[0] * bf2f(K[0]); \
    float pb_ = qd[1] * bf2f(K[1]); \
    pa_ = fmaf(qd[2], bf2f(K[2]), pa_); \
    pb_ = fmaf(qd[3], bf2f(K[3]), pb_); \
    pa_ = fmaf(qd[4], bf2f(K[4]), pa_); \
    pb_ = fmaf(qd[5], bf2f(K[5]), pb_); \
    pa_ = fmaf(qd[6], bf2f(K[6]), pa_); \
    pb_ = fmaf(qd[7], bf2f(K[7]), pb_); \
    float p_ = pa_ + pb_; \
    p_ = dpp_xadd<0xB1>(p_); \
    p_ = dpp_xadd<0x4E>(p_); \
    const float e_ = ((base) + half < deg) ? exp2f(p_) : 0.f; \
    z += e_; \
    o[0] = fmaf(e_, bf2f(V[0]), o[0]); \
    o[1] = fmaf(e_, bf2f(V[1]), o[1]); \
    o[2] = fmaf(e_, bf2f(V[2]), o[2]); \
    o[3] = fmaf(e_, bf2f(V[3]), o[3]); \
    o[4] = fmaf(e_, bf2f(V[4]), o[4]); \
    o[5] = fmaf(e_, bf2f(V[5]), o[5]); \
    o[6] = fmaf(e_, bf2f(V[6]), o[6]); \
    o[7] = fmaf(e_, bf2f(V[7]), o[7]); \
} while (0)

    if (deg > 0) {
        u16x8 ak0, av0, ak1, av1, bk0, bv0, bk1, bv1;
        LP(ak0, av0, 0);
        LP(ak1, av1, 2);
        for (int i0 = 0; i0 < deg; i0 += 8) {
            const bool hb = (i0 + 4) < deg;
            if (hb) { LP(bk0, bv0, i0 + 4); LP(bk1, bv1, i0 + 6); }
            CMP(ak0, av0, i0);
            CMP(ak1, av1, i0 + 2);
            if (i0 + 8 < deg) { LP(ak0, av0, i0 + 8); LP(ak1, av1, i0 + 10); }
            if (hb) { CMP(bk0, bv0, i0 + 4); CMP(bk1, bv1, i0 + 6); }
        }
    }
#undef LP
#undef CMP

    z += __shfl_xor(z, 32);
    #pragma unroll
    for (int d = 0; d < 8; ++d) o[d] += __shfl_xor(o[d], 32);

    if (half == 0) {
        u16x8 r;
        if (deg > 0) {
            const float iz = 1.0f / z;
            #pragma unroll
            for (int d = 0; d < 8; ++d) r[d] = f2bf(o[d] * iz);
        } else {
            #pragma unroll
            for (int d = 0; d < 8; ++d) r[d] = 0;
        }
        *reinterpret_cast<u16x8*>(&ot[row * 256 + w5 * 8]) = r;
    }
}

// ---------------------------------------------------------------------------
extern "C" void kernel_launch(void* const* d_in, const int* in_sizes, int n_in,
                              void* d_out, int out_size, void* d_ws, size_t ws_size,
                              hipStream_t stream)
{
    const float* h  = (const float*)d_in[0];
    const float* Wq = (const float*)d_in[1];
    const float* bq = (const float*)d_in[2];
    const float* Wk = (const float*)d_in[3];
    const float* bk = (const float*)d_in[4];
    const float* Wv = (const float*)d_in[5];
    const float* bv = (const float*)d_in[6];
    const float* Wo = (const float*)d_in[7];
    const float* bo = (const float*)d_in[8];
    const int* rows = (const int*)d_in[9];
    const int* cols = (const int*)d_in[10];
    float* outp = (float*)d_out;

    // workspace layout (bytes), 16B-aligned; total ~53.3 MB
    char* ws = (char*)d_ws;
    unsigned short* q_b  = (unsigned short*)(ws + 0);          // 10,240,000
    unsigned short* kv_b = (unsigned short*)(ws + 10240000);   // 20,480,000
    unsigned short* ot_b = (unsigned short*)(ws + 30720000);   // 10,240,000
    unsigned short* h_b  = (unsigned short*)(ws + 40960000);   // 10,240,000
    unsigned short* wt   = (unsigned short*)(ws + 51200000);   // 524,288
    float* bp            = (float*)(ws + 51724288);            // 3,072
    int* row_start       = (int*)(ws + 51727360);              // 80,004
    int* counts          = (int*)(ws + 51807488);              // 80,000
    int* cursor          = (int*)(ws + 51887488);              // 80,000
    int* cols_sorted     = (int*)(ws + 51967488);              // 1,280,000 + pad

    hipMemsetAsync(ws + 51807488, 0, 160000, stream);          // counts + cursor

    prep_all_k<<<7277, 256, 0, stream>>>(Wq, bq, Wk, bk, Wv, bv, Wo, rows, h,
                                         wt, bp, counts, h_b);
    scan_k<<<1, 1024, 0, stream>>>(counts, row_start);
    scatter_k<<<1250, 256, 0, stream>>>(rows, cols, row_start, cursor, cols_sorted);
    qkv_mfma_k<<<dim3(313, 6), 256, 0, stream>>>(h_b, wt, bp, q_b, kv_b);
    row_attn_k<<<5000, 256, 0, stream>>>(q_b, kv_b, row_start, cols_sorted, ot_b);
    out_mfma_k<<<dim3(313, 2), 256, 0, stream>>>(ot_b, wt, bo, outp);
}